// Round 20
// baseline (224.334 us; speedup 1.0000x reference)
//
#include <hip/hip_runtime.h>
#include <stdint.h>

#define SEQ   2048
#define BATCH 4
#define NH    16
#define HD    64
#define HID   1024
#define NPOS  73

typedef __attribute__((ext_vector_type(8))) short short8;
typedef __attribute__((ext_vector_type(4))) short short4v;
typedef __attribute__((ext_vector_type(4))) float f32x4;

static __device__ __forceinline__ float bf2f(short s) {
  return __uint_as_float(((unsigned)(unsigned short)s) << 16);
}
static __device__ __forceinline__ short f2bf(float f) {
  unsigned u = __float_as_uint(f);
  u += 0x7fffu + ((u >> 16) & 1u);
  return (short)(u >> 16);
}
// packed f32x2 -> bf16x2 (RNE), no builtin on gfx950 -> inline asm
static __device__ __forceinline__ unsigned pkbf(float a, float b) {
  unsigned d;
  asm("v_cvt_pk_bf16_f32 %0, %1, %2" : "=v"(d) : "v"(a), "v"(b));
  return d;
}

static __device__ __forceinline__ void gload_lds16(const void* g, void* lds) {
  __builtin_amdgcn_global_load_lds(
      (const __attribute__((address_space(1))) unsigned int*)g,
      (__attribute__((address_space(3))) unsigned int*)lds, 16, 0, 0);
}

// Single fused fp32->bf16 conversion for ALL inputs (hs | Wq Wk Wv Wo | de).
// Segment boundaries fall exactly on block boundaries: hs = 2^21 f32x4 slots
// (blocks 0..8191), each weight = 2^18 slots (1024 blocks each), de = 1168
// slots starting at block 12288. Pointer selects are block-uniform.
__global__ __launch_bounds__(256) void cvt_all(const float* __restrict__ hs,
                                               const float* __restrict__ Wq,
                                               const float* __restrict__ Wk,
                                               const float* __restrict__ Wv,
                                               const float* __restrict__ Wo,
                                               const float* __restrict__ de,
                                               short* __restrict__ o_hs,
                                               short* __restrict__ o_wq,
                                               short* __restrict__ o_wk,
                                               short* __restrict__ o_wv,
                                               short* __restrict__ o_wo,
                                               short* __restrict__ o_de) {
  const long HS4 = (long)BATCH * SEQ * HID / 4;       // 2,097,152
  const long W4  = (long)HID * HID / 4;               //   262,144
  const long DE4 = NPOS * HD / 4;                     //     1,168
  long i = (long)blockIdx.x * 256 + threadIdx.x;
  const float* in;
  short* out;
  long off;
  if (i < HS4) {
    in = hs; out = o_hs; off = i;
  } else if (i < HS4 + 4 * W4) {
    long j = i - HS4;
    int k = (int)(j >> 18);               // W4 = 2^18
    off = j & (W4 - 1);
    in = k == 0 ? Wq : k == 1 ? Wk : k == 2 ? Wv : Wo;
    out = k == 0 ? o_wq : k == 1 ? o_wk : k == 2 ? o_wv : o_wo;
  } else if (i < HS4 + 4 * W4 + DE4) {
    in = de; out = o_de; off = i - HS4 - 4 * W4;
  } else {
    return;
  }
  f32x4 f = *(const f32x4*)(in + off * 4);
  short4v o;
  o[0] = f2bf(f[0]); o[1] = f2bf(f[1]); o[2] = f2bf(f[2]); o[3] = f2bf(f[3]);
  *(short4v*)(out + off * 4) = o;
}

// C = A * B^T + bias. A:[M,K] bf16 row-major, B:[N,K] bf16 row-major (NT).
// MODE 0: bf16 out scattered to [b,h,l,d]; MODE 1: fp32 out [M,HID];
// MODE 2: bf16 out scattered transposed to [b,h,d,l] (V^T)
// (round-14 verified BK=32 structure — BK=64 regressed via occupancy, r17)
template <int MODE>
__global__ __launch_bounds__(256) void gemm_nt(const short* __restrict__ A,
                                               const short* __restrict__ B,
                                               const float* __restrict__ bias,
                                               void* __restrict__ Cout, float scale) {
  __shared__ __align__(16) short As[128 * 32];
  __shared__ __align__(16) short Bs[128 * 32];
  const int K = HID;
  const f32x4 fzero = {0.f, 0.f, 0.f, 0.f};
  int t = threadIdx.x;
  int w = t >> 6, lane = t & 63;
  int wr = w >> 1, wc = w & 1;
  int g = lane >> 4, r = lane & 15;
  long tile_m = (long)blockIdx.x * 128;
  long tile_n = (long)blockIdx.y * 128;

  f32x4 acc[4][4];
#pragma unroll
  for (int m = 0; m < 4; ++m)
#pragma unroll
    for (int n = 0; n < 4; ++n) acc[m][n] = fzero;

  int e0 = w * 1024 + lane * 8;
  int e1 = e0 + 512;
  const short* A0 = A + (tile_m + (e0 >> 5)) * K + (e0 & 31);
  const short* A1 = A + (tile_m + (e1 >> 5)) * K + (e1 & 31);
  const short* B0 = B + (tile_n + (e0 >> 5)) * K + (e0 & 31);
  const short* B1 = B + (tile_n + (e1 >> 5)) * K + (e1 & 31);

  for (int k0 = 0; k0 < K; k0 += 32) {
    __syncthreads();
    gload_lds16(A0 + k0, &As[e0]);
    gload_lds16(A1 + k0, &As[e1]);
    gload_lds16(B0 + k0, &Bs[e0]);
    gload_lds16(B1 + k0, &Bs[e1]);
    __syncthreads();
    short8 af[4], bfr[4];
#pragma unroll
    for (int m = 0; m < 4; ++m)
      af[m] = *(const short8*)&As[(wr * 64 + m * 16 + r) * 32 + g * 8];
#pragma unroll
    for (int n = 0; n < 4; ++n)
      bfr[n] = *(const short8*)&Bs[(wc * 64 + n * 16 + r) * 32 + g * 8];
#pragma unroll
    for (int m = 0; m < 4; ++m)
#pragma unroll
      for (int n = 0; n < 4; ++n)
        acc[m][n] = __builtin_amdgcn_mfma_f32_16x16x32_bf16(af[m], bfr[n], acc[m][n], 0, 0, 0);
  }

#pragma unroll
  for (int m = 0; m < 4; ++m) {
    int row0 = (int)tile_m + wr * 64 + m * 16 + g * 4;
#pragma unroll
    for (int n = 0; n < 4; ++n) {
      int col = (int)tile_n + wc * 64 + n * 16 + r;
      float bs = bias[col];
#pragma unroll
      for (int j = 0; j < 4; ++j) {
        int row = row0 + j;
        float val = (acc[m][n][j] + bs) * scale;
        if (MODE == 0) {
          int b = row >> 11, l = row & (SEQ - 1);
          int hh = col >> 6, d = col & 63;
          ((short*)Cout)[(((long)(b * NH + hh) * SEQ + l) << 6) + d] = f2bf(val);
        } else if (MODE == 2) {
          int b = row >> 11, l = row & (SEQ - 1);
          int hh = col >> 6, d = col & 63;
          ((short*)Cout)[(((long)(b * NH + hh) * HD + d) << 11) + l] = f2bf(val);
        } else {
          ((float*)Cout)[(long)row * HID + col] = val;
        }
      }
    }
  }
}

// qd[row][p] = sum_d Q[row][d] * DE[p][d]  (row-flat over [b,h,l], p < 73).
__global__ __launch_bounds__(256) void qd_kernel(const short* __restrict__ Q,
                                                 const short* __restrict__ DE,
                                                 short* __restrict__ qd) {
  __shared__ __align__(16) short Qs[128 * 64];  // 16 KB
  __shared__ __align__(16) short Es[80 * 64];   // 10 KB (rows 73..79 unused)
  const f32x4 fzero = {0.f, 0.f, 0.f, 0.f};
  int t = threadIdx.x;
  int w = t >> 6, lane = t & 63;
  int g = lane >> 4, r = lane & 15;
  const short* Qp = Q + (long)blockIdx.x * (128 * 64);

#pragma unroll
  for (int c = 0; c < 4; ++c)
    gload_lds16(Qp + c * 2048 + t * 8, &Qs[c * 2048 + t * 8]);
#pragma unroll
  for (int i = 0; i < 3; ++i) {
    int s = i * 256 + t;                 // 16B slot; 73*64/8 = 584 slots
    if (s < 584) gload_lds16(DE + s * 8, &Es[s * 8]);
  }
  __syncthreads();

  short8 af[2][2];
#pragma unroll
  for (int m = 0; m < 2; ++m)
#pragma unroll
    for (int kb = 0; kb < 2; ++kb)
      af[m][kb] = *(const short8*)&Qs[(w * 32 + m * 16 + r) * 64 + kb * 32 + g * 8];

  f32x4 acc[2][5];
#pragma unroll
  for (int m = 0; m < 2; ++m)
#pragma unroll
    for (int n = 0; n < 5; ++n) acc[m][n] = fzero;

#pragma unroll
  for (int kb = 0; kb < 2; ++kb)
#pragma unroll
    for (int n = 0; n < 5; ++n) {
      short8 bfr = *(const short8*)&Es[(n * 16 + r) * 64 + kb * 32 + g * 8];
#pragma unroll
      for (int m = 0; m < 2; ++m)
        acc[m][n] = __builtin_amdgcn_mfma_f32_16x16x32_bf16(af[m][kb], bfr, acc[m][n], 0, 0, 0);
    }

  int p = r;  // col = n*16 + r
#pragma unroll
  for (int m = 0; m < 2; ++m) {
#pragma unroll
    for (int n = 0; n < 5; ++n) {
      int pp = n * 16 + p;
      if (pp < NPOS) {
#pragma unroll
        for (int j = 0; j < 4; ++j) {
          long row = (long)blockIdx.x * 128 + w * 32 + m * 16 + g * 4 + j;
          qd[row * NPOS + pp] = f2bf(acc[m][n][j]);
        }
      }
    }
  }
}

// Flash attention (round-14 structure) + T4 COUNTED-vmcnt pipeline:
// __syncthreads drains vmcnt(0), killing the next-tile prefetch every
// iteration (r12's "2-phase" never pipelined). Replaced with per-wave
// s_waitcnt vmcnt(4) (oldest 4 = current tile; each wave vouches for its
// own stages) + raw s_barrier at iteration start, and lgkmcnt(0) + raw
// s_barrier at iteration end (this wave's LDS reads returned before the
// next iteration's DMA may overwrite the buffer). Next-tile loads stay in
// flight across both barriers — true latency hiding (catalog T4; AITER
// vmcnt(2/5/12)-never-0 pattern). Gather-path qd vmem loads sit between
// the two staging groups in age order, so vmcnt(4) only gets stricter.
// Swapped-operand layout, log2 domain, NO-SHIFT softmax (p = exp2(s+b)).
// l via ones-MFMA. qd precomputed in global; LDS = K/V dbuf (32 KB).
// grid (NH*BATCH, SEQ/128) for XCD K/V L2 locality. V pre-transposed
// [b,h,d,l]. 16B-slot XOR swizzle via pre-swizzled global source.
__global__ __launch_bounds__(256, 3) void attn_kernel(const short* __restrict__ Qg,
                                                      const short* __restrict__ Kg,
                                                      const short* __restrict__ Vg,
                                                      const short* __restrict__ qdG,
                                                      short* __restrict__ ctx) {
  // arena 32K: buf0 {Ks 8K | Vt 8K} @0, buf1 @16384. Prologue alias: Qs@0 (16K)
  __shared__ __align__(16) char arena[32768];
  short* Qs = (short*)arena;  // prologue alias

  const f32x4 fzero = {0.f, 0.f, 0.f, 0.f};
  int t = threadIdx.x;
  int w = t >> 6, lane = t & 63;
  int g = lane >> 4, r = lane & 15;
  int h = blockIdx.x & (NH - 1), b = blockIdx.x >> 4, qt = blockIdx.y;
  int q0 = qt * 128;
  const short* Qp = Qg + ((long)(b * NH + h) * SEQ + q0) * HD;
  const short* Kp = Kg + (long)(b * NH + h) * SEQ * HD;
  const short* VTp = Vg + (long)(b * NH + h) * HD * SEQ;  // [d][l]

  // ---- prologue: stage Q (linear, 16KB = 4 chunks x 256 lanes x 16B) ----
#pragma unroll
  for (int c = 0; c < 4; ++c)
    gload_lds16(Qp + c * 2048 + t * 8, &Qs[c * 2048 + t * 8]);
  __syncthreads();

  // hoist Q B-fragments: wave w owns q rows w*32..w*32+31, sub-tiles hq=0,1
  short8 aq[2][2];
#pragma unroll
  for (int hq = 0; hq < 2; ++hq)
#pragma unroll
    for (int kb = 0; kb < 2; ++kb)
      aq[hq][kb] = *(const short8*)&Qs[(w * 32 + hq * 16 + r) * 64 + kb * 32 + g * 8];
  __syncthreads();  // all Qs reads done; buf0 reusable

  // per-q bias rows in global qd (computed by qd_kernel)
  long qrow0 = (long)(b * NH + h) * SEQ + q0 + w * 32 + r;
  long qrow1 = qrow0 + 16;
  const short* qd0 = qdG + qrow0 * NPOS;
  const short* qd1 = qdG + qrow1 * NPOS;
  float bl0 = bf2f(qd0[0]), br0 = bf2f(qd0[72]);
  float bl1 = bf2f(qd1[0]), br1 = bf2f(qd1[72]);

  // staging sources (16B-slot XOR swizzle via global address, linear rows)
  int srow = lane >> 3;
  int ssl = ((lane & 7) ^ srow) * 8;
  const short* K0 = Kp + (long)(w * 16 + srow) * HD + ssl;
  const short* K1 = Kp + (long)(w * 16 + 8 + srow) * HD + ssl;
  const short* V0 = VTp + (long)(w * 16 + srow) * SEQ + ssl;
  const short* V1 = VTp + (long)(w * 16 + 8 + srow) * SEQ + ssl;
  int e0 = w * 1024 + lane * 8;
  int e1 = e0 + 512;
  int rx = (r & 7) << 3;
  int Lw = q0 + w * 32;

  // pipeline prologue: stage tile 0 into buf0 (Qs is dead past the barrier)
  {
    short* kb = (short*)arena;
    short* vb = kb + 4096;
    gload_lds16(K0, &kb[e0]);
    gload_lds16(K1, &kb[e1]);
    gload_lds16(V0, &vb[e0]);
    gload_lds16(V1, &vb[e1]);
  }
  __syncthreads();  // tile 0 staged (full drain OK here; nothing else in flight)

  f32x4 o0[4], o1[4], lc0 = fzero, lc1 = fzero;
#pragma unroll
  for (int n = 0; n < 4; ++n) { o0[n] = fzero; o1[n] = fzero; }

  const short8 ones8 = {0x3F80, 0x3F80, 0x3F80, 0x3F80, 0x3F80, 0x3F80, 0x3F80, 0x3F80};
  union U8 { unsigned u[4]; short8 v; };

  for (int kt = 0; kt < 32; ++kt) {
    // stage NEXT tile into the other buffer; its 4 loads stay in flight
    // across both barriers (counted vmcnt below — never drained to 0).
    {
      int kvn = ((kt + 1) & 31) * 64;   // kt=31 wraps: harmless restage of tile 0
      short* kb = (short*)(arena + (((kt + 1) & 1) << 14));
      short* vb = kb + 4096;
      gload_lds16(K0 + (long)kvn * HD, &kb[e0]);
      gload_lds16(K1 + (long)kvn * HD, &kb[e1]);
      gload_lds16(V0 + kvn, &vb[e0]);
      gload_lds16(V1 + kvn, &vb[e1]);
    }
    // T4: wait only the oldest loads (current tile); leave the 4 newest
    // (next tile) in flight. Each wave vouches for its own stages; the
    // barrier makes tile kt collectively visible.
    asm volatile("s_waitcnt vmcnt(4)" ::: "memory");
    __builtin_amdgcn_s_barrier();

    const short* Ks = (const short*)(arena + ((kt & 1) << 14));
    const short* Vt = Ks + 4096;
    int kv0 = kt * 64;

    // S^T = K Q^T: C rows = keys (n*16+g*4+j), col = q (r). K-frag shared hq.
    f32x4 s0[4], s1[4];
#pragma unroll
    for (int n = 0; n < 4; ++n) { s0[n] = fzero; s1[n] = fzero; }
#pragma unroll
    for (int kb = 0; kb < 2; ++kb)
#pragma unroll
      for (int n = 0; n < 4; ++n) {
        short8 kfr = *(const short8*)&Ks[(n * 16 + r) * 64 + ((kb * 32 + g * 8) ^ rx)];
        s0[n] = __builtin_amdgcn_mfma_f32_16x16x32_bf16(kfr, aq[0][kb], s0[n], 0, 0, 0);
        s1[n] = __builtin_amdgcn_mfma_f32_16x16x32_bf16(kfr, aq[1][kb], s1[n], 0, 0, 0);
      }

    // relative bias: wave-uniform clamped fast path (29/32 tiles), then
    // p = exp2(s + b) directly — no max subtraction (shift-free softmax)
    bool allL = (kv0 + 63) <= (Lw - 64);
    bool allR = kv0 >= (Lw + 31 + 8);
    if (allL || allR) {
      float b0 = allL ? bl0 : br0;
      float b1 = allL ? bl1 : br1;
#pragma unroll
      for (int n = 0; n < 4; ++n)
#pragma unroll
        for (int j = 0; j < 4; ++j) { s0[n][j] += b0; s1[n][j] += b1; }
    } else {
      int lq = q0 + w * 32 + r;
#pragma unroll
      for (int n = 0; n < 4; ++n) {
        int key = kv0 + n * 16 + g * 4;
#pragma unroll
        for (int j = 0; j < 4; ++j) {
          int d0i = key + j - lq;
          d0i = d0i < -64 ? -64 : (d0i > 8 ? 8 : d0i);
          int d1i = key + j - lq - 16;
          d1i = d1i < -64 ? -64 : (d1i > 8 ? 8 : d1i);
          s0[n][j] += bf2f(qd0[d0i + 64]);
          s1[n][j] += bf2f(qd1[d1i + 64]);
        }
      }
    }

#pragma unroll
    for (int n = 0; n < 4; ++n)
#pragma unroll
      for (int j = 0; j < 4; ++j) {
        s0[n][j] = __builtin_amdgcn_exp2f(s0[n][j]);
        s1[n][j] = __builtin_amdgcn_exp2f(s1[n][j]);
      }

    // O^T += V^T P^T : A = V^T-frag (k-permuted to match), B = P from regs.
    // l accumulated by ones-MFMA (order-immune sum over all 32 keys).
#pragma unroll
    for (int w32 = 0; w32 < 2; ++w32) {
      U8 pb0, pb1;
      pb0.u[0] = pkbf(s0[2 * w32][0], s0[2 * w32][1]);
      pb0.u[1] = pkbf(s0[2 * w32][2], s0[2 * w32][3]);
      pb0.u[2] = pkbf(s0[2 * w32 + 1][0], s0[2 * w32 + 1][1]);
      pb0.u[3] = pkbf(s0[2 * w32 + 1][2], s0[2 * w32 + 1][3]);
      pb1.u[0] = pkbf(s1[2 * w32][0], s1[2 * w32][1]);
      pb1.u[1] = pkbf(s1[2 * w32][2], s1[2 * w32][3]);
      pb1.u[2] = pkbf(s1[2 * w32 + 1][0], s1[2 * w32 + 1][1]);
      pb1.u[3] = pkbf(s1[2 * w32 + 1][2], s1[2 * w32 + 1][3]);
      lc0 = __builtin_amdgcn_mfma_f32_16x16x32_bf16(ones8, pb0.v, lc0, 0, 0, 0);
      lc1 = __builtin_amdgcn_mfma_f32_16x16x32_bf16(ones8, pb1.v, lc1, 0, 0, 0);
      // V^T cols w32*32 + {g*4..+3, 16+g*4..+3}, 16B-slot swizzled by row
      int cA = (((w32 * 4 + (g >> 1)) ^ (r & 7)) << 3) + ((g & 1) * 4);
      int cB = (((w32 * 4 + 2 + (g >> 1)) ^ (r & 7)) << 3) + ((g & 1) * 4);
#pragma unroll
      for (int n = 0; n < 4; ++n) {
        const short* vrow = &Vt[(n * 16 + r) * 64];
        short4v va_ = *(const short4v*)(vrow + cA);
        short4v vb_ = *(const short4v*)(vrow + cB);
        short8 v8;
        v8[0] = va_[0]; v8[1] = va_[1]; v8[2] = va_[2]; v8[3] = va_[3];
        v8[4] = vb_[0]; v8[5] = vb_[1]; v8[6] = vb_[2]; v8[7] = vb_[3];
        o0[n] = __builtin_amdgcn_mfma_f32_16x16x32_bf16(v8, pb0.v, o0[n], 0, 0, 0);
        o1[n] = __builtin_amdgcn_mfma_f32_16x16x32_bf16(v8, pb1.v, o1[n], 0, 0, 0);
      }
    }
    // end-of-iteration: this wave's LDS reads returned (lgkmcnt only — the
    // in-flight next-tile DMA must NOT be drained), then rendezvous so no
    // wave's next-next-tile DMA can overwrite a buffer still being read.
    asm volatile("s_waitcnt lgkmcnt(0)" ::: "memory");
    __builtin_amdgcn_s_barrier();
  }

  // epilogue: lc cols hold full l for q=r (rows identical); normalize, store
  float inv0 = 1.f / lc0[0], inv1 = 1.f / lc1[0];
  long grow0 = (long)(b * SEQ + q0 + w * 32 + r);
  long grow1 = grow0 + 16;
#pragma unroll
  for (int n = 0; n < 4; ++n) {
    uint2 v0, v1;
    v0.x = pkbf(o0[n][0] * inv0, o0[n][1] * inv0);
    v0.y = pkbf(o0[n][2] * inv0, o0[n][3] * inv0);
    v1.x = pkbf(o1[n][0] * inv1, o1[n][1] * inv1);
    v1.y = pkbf(o1[n][2] * inv1, o1[n][3] * inv1);
    *(uint2*)&ctx[grow0 * HID + h * 64 + n * 16 + g * 4] = v0;
    *(uint2*)&ctx[grow1 * HID + h * 64 + n * 16 + g * 4] = v1;
  }
}

extern "C" void kernel_launch(void* const* d_in, const int* in_sizes, int n_in,
                              void* d_out, int out_size, void* d_ws, size_t ws_size,
                              hipStream_t stream) {
  if (n_in < 10) return;
  const float* hs = (const float*)d_in[0];
  const float* Wq = (const float*)d_in[1];
  const float* bq = (const float*)d_in[2];
  const float* Wk = (const float*)d_in[3];
  const float* bk = (const float*)d_in[4];
  const float* Wv = (const float*)d_in[5];
  const float* bv = (const float*)d_in[6];
  const float* Wo = (const float*)d_in[7];
  const float* bo = (const float*)d_in[8];
  const float* de = (const float*)d_in[9];

  char* ws = (char*)d_ws;
  size_t off = 0;
  auto alloc = [&](size_t bytes) {
    size_t o = off;
    off += (bytes + 255) & ~(size_t)255;
    return o;
  };
  const size_t ACT = (size_t)BATCH * SEQ * HID * 2;  // 16 MB bf16
  const size_t WMT = (size_t)HID * HID * 2;          // 2 MB bf16
  short* hB  = (short*)(ws + alloc(ACT));
  short* wqB = (short*)(ws + alloc(WMT));
  short* wkB = (short*)(ws + alloc(WMT));
  short* wvB = (short*)(ws + alloc(WMT));
  short* woB = (short*)(ws + alloc(WMT));
  short* deB = (short*)(ws + alloc((size_t)NPOS * HD * 2));
  short* qB  = (short*)(ws + alloc(ACT));
  short* kB  = (short*)(ws + alloc(ACT));
  short* vB  = (short*)(ws + alloc(ACT));  // V^T layout [b,h,d,l]
  short* qdB = (short*)(ws + alloc((size_t)BATCH * NH * SEQ * NPOS * 2));  // 19.1 MB
  short* ctxB = hB;  // hB dead after QKV GEMMs; reuse for attention output

  // one fused conversion launch: hs (8192 blocks) | 4 weights (4096) | de (5)
  {
    long total4 = (long)BATCH * SEQ * HID / 4 + 4L * (HID * HID / 4) + NPOS * HD / 4;
    int nblk = (int)((total4 + 255) / 256);
    cvt_all<<<dim3(nblk), dim3(256), 0, stream>>>(hs, Wq, Wk, Wv, Wo, de,
                                                  hB, wqB, wkB, wvB, woB, deB);
  }

  // Q pre-scaled by (1/sqrt(64)) * log2(e) so attention works in exp2 domain
  const float QSCALE = 0.125f * 1.4426950408889634f;
  dim3 gg(BATCH * SEQ / 128, HID / 128), blk(256);
  gemm_nt<0><<<gg, blk, 0, stream>>>(hB, wqB, bq, qB, QSCALE);
  gemm_nt<0><<<gg, blk, 0, stream>>>(hB, wkB, bk, kB, 1.0f);
  gemm_nt<2><<<gg, blk, 0, stream>>>(hB, wvB, bv, vB, 1.0f);    // V transposed

  // qd[row][p] = Q·DE^T (inherits QSCALE*log2e from qB) — 2.4 GFLOP MFMA
  qd_kernel<<<dim3(BATCH * NH * SEQ / 128), blk, 0, stream>>>(qB, deB, qdB);

  attn_kernel<<<dim3(NH * BATCH, SEQ / 128), blk, 0, stream>>>(qB, kB, vB, qdB, ctxB);

  gemm_nt<1><<<gg, blk, 0, stream>>>(ctxB, woB, bo, d_out, 1.0f);
}

// Round 21
// 222.920 us; speedup vs baseline: 1.0063x; 1.0063x over previous
//
#include <hip/hip_runtime.h>
#include <stdint.h>

#define SEQ   2048
#define BATCH 4
#define NH    16
#define HD    64
#define HID   1024
#define NPOS  73

typedef __attribute__((ext_vector_type(8))) short short8;
typedef __attribute__((ext_vector_type(4))) short short4v;
typedef __attribute__((ext_vector_type(4))) float f32x4;

static __device__ __forceinline__ float bf2f(short s) {
  return __uint_as_float(((unsigned)(unsigned short)s) << 16);
}
static __device__ __forceinline__ short f2bf(float f) {
  unsigned u = __float_as_uint(f);
  u += 0x7fffu + ((u >> 16) & 1u);
  return (short)(u >> 16);
}
// packed f32x2 -> bf16x2 (RNE), no builtin on gfx950 -> inline asm
static __device__ __forceinline__ unsigned pkbf(float a, float b) {
  unsigned d;
  asm("v_cvt_pk_bf16_f32 %0, %1, %2" : "=v"(d) : "v"(a), "v"(b));
  return d;
}

static __device__ __forceinline__ void gload_lds16(const void* g, void* lds) {
  __builtin_amdgcn_global_load_lds(
      (const __attribute__((address_space(1))) unsigned int*)g,
      (__attribute__((address_space(3))) unsigned int*)lds, 16, 0, 0);
}

// Single fused fp32->bf16 conversion for ALL inputs (hs | Wq Wk Wv Wo | de).
// Segment boundaries fall exactly on block boundaries: hs = 2^21 f32x4 slots
// (blocks 0..8191), each weight = 2^18 slots (1024 blocks each), de = 1168
// slots starting at block 12288. Pointer selects are block-uniform.
__global__ __launch_bounds__(256) void cvt_all(const float* __restrict__ hs,
                                               const float* __restrict__ Wq,
                                               const float* __restrict__ Wk,
                                               const float* __restrict__ Wv,
                                               const float* __restrict__ Wo,
                                               const float* __restrict__ de,
                                               short* __restrict__ o_hs,
                                               short* __restrict__ o_wq,
                                               short* __restrict__ o_wk,
                                               short* __restrict__ o_wv,
                                               short* __restrict__ o_wo,
                                               short* __restrict__ o_de) {
  const long HS4 = (long)BATCH * SEQ * HID / 4;       // 2,097,152
  const long W4  = (long)HID * HID / 4;               //   262,144
  const long DE4 = NPOS * HD / 4;                     //     1,168
  long i = (long)blockIdx.x * 256 + threadIdx.x;
  const float* in;
  short* out;
  long off;
  if (i < HS4) {
    in = hs; out = o_hs; off = i;
  } else if (i < HS4 + 4 * W4) {
    long j = i - HS4;
    int k = (int)(j >> 18);               // W4 = 2^18
    off = j & (W4 - 1);
    in = k == 0 ? Wq : k == 1 ? Wk : k == 2 ? Wv : Wo;
    out = k == 0 ? o_wq : k == 1 ? o_wk : k == 2 ? o_wv : o_wo;
  } else if (i < HS4 + 4 * W4 + DE4) {
    in = de; out = o_de; off = i - HS4 - 4 * W4;
  } else {
    return;
  }
  f32x4 f = *(const f32x4*)(in + off * 4);
  short4v o;
  o[0] = f2bf(f[0]); o[1] = f2bf(f[1]); o[2] = f2bf(f[2]); o[3] = f2bf(f[3]);
  *(short4v*)(out + off * 4) = o;
}

// C = A * B^T + bias. A:[M,K] bf16 row-major, B:[N,K] bf16 row-major (NT).
// MODE 0: bf16 out scattered to [b,h,l,d]; MODE 1: fp32 out [M,HID];
// MODE 2: bf16 out scattered transposed to [b,h,d,l] (V^T)
// (round-14 verified BK=32 structure — BK=64 regressed via occupancy, r17)
template <int MODE>
__global__ __launch_bounds__(256) void gemm_nt(const short* __restrict__ A,
                                               const short* __restrict__ B,
                                               const float* __restrict__ bias,
                                               void* __restrict__ Cout, float scale) {
  __shared__ __align__(16) short As[128 * 32];
  __shared__ __align__(16) short Bs[128 * 32];
  const int K = HID;
  const f32x4 fzero = {0.f, 0.f, 0.f, 0.f};
  int t = threadIdx.x;
  int w = t >> 6, lane = t & 63;
  int wr = w >> 1, wc = w & 1;
  int g = lane >> 4, r = lane & 15;
  long tile_m = (long)blockIdx.x * 128;
  long tile_n = (long)blockIdx.y * 128;

  f32x4 acc[4][4];
#pragma unroll
  for (int m = 0; m < 4; ++m)
#pragma unroll
    for (int n = 0; n < 4; ++n) acc[m][n] = fzero;

  int e0 = w * 1024 + lane * 8;
  int e1 = e0 + 512;
  const short* A0 = A + (tile_m + (e0 >> 5)) * K + (e0 & 31);
  const short* A1 = A + (tile_m + (e1 >> 5)) * K + (e1 & 31);
  const short* B0 = B + (tile_n + (e0 >> 5)) * K + (e0 & 31);
  const short* B1 = B + (tile_n + (e1 >> 5)) * K + (e1 & 31);

  for (int k0 = 0; k0 < K; k0 += 32) {
    __syncthreads();
    gload_lds16(A0 + k0, &As[e0]);
    gload_lds16(A1 + k0, &As[e1]);
    gload_lds16(B0 + k0, &Bs[e0]);
    gload_lds16(B1 + k0, &Bs[e1]);
    __syncthreads();
    short8 af[4], bfr[4];
#pragma unroll
    for (int m = 0; m < 4; ++m)
      af[m] = *(const short8*)&As[(wr * 64 + m * 16 + r) * 32 + g * 8];
#pragma unroll
    for (int n = 0; n < 4; ++n)
      bfr[n] = *(const short8*)&Bs[(wc * 64 + n * 16 + r) * 32 + g * 8];
#pragma unroll
    for (int m = 0; m < 4; ++m)
#pragma unroll
      for (int n = 0; n < 4; ++n)
        acc[m][n] = __builtin_amdgcn_mfma_f32_16x16x32_bf16(af[m], bfr[n], acc[m][n], 0, 0, 0);
  }

#pragma unroll
  for (int m = 0; m < 4; ++m) {
    int row0 = (int)tile_m + wr * 64 + m * 16 + g * 4;
#pragma unroll
    for (int n = 0; n < 4; ++n) {
      int col = (int)tile_n + wc * 64 + n * 16 + r;
      float bs = bias[col];
#pragma unroll
      for (int j = 0; j < 4; ++j) {
        int row = row0 + j;
        float val = (acc[m][n][j] + bs) * scale;
        if (MODE == 0) {
          int b = row >> 11, l = row & (SEQ - 1);
          int hh = col >> 6, d = col & 63;
          ((short*)Cout)[(((long)(b * NH + hh) * SEQ + l) << 6) + d] = f2bf(val);
        } else if (MODE == 2) {
          int b = row >> 11, l = row & (SEQ - 1);
          int hh = col >> 6, d = col & 63;
          ((short*)Cout)[(((long)(b * NH + hh) * HD + d) << 11) + l] = f2bf(val);
        } else {
          ((float*)Cout)[(long)row * HID + col] = val;
        }
      }
    }
  }
}

// qd[row][p] = sum_d Q[row][d] * DE[p][d]  (row-flat over [b,h,l], p < 73).
__global__ __launch_bounds__(256) void qd_kernel(const short* __restrict__ Q,
                                                 const short* __restrict__ DE,
                                                 short* __restrict__ qd) {
  __shared__ __align__(16) short Qs[128 * 64];  // 16 KB
  __shared__ __align__(16) short Es[80 * 64];   // 10 KB (rows 73..79 unused)
  const f32x4 fzero = {0.f, 0.f, 0.f, 0.f};
  int t = threadIdx.x;
  int w = t >> 6, lane = t & 63;
  int g = lane >> 4, r = lane & 15;
  const short* Qp = Q + (long)blockIdx.x * (128 * 64);

#pragma unroll
  for (int c = 0; c < 4; ++c)
    gload_lds16(Qp + c * 2048 + t * 8, &Qs[c * 2048 + t * 8]);
#pragma unroll
  for (int i = 0; i < 3; ++i) {
    int s = i * 256 + t;                 // 16B slot; 73*64/8 = 584 slots
    if (s < 584) gload_lds16(DE + s * 8, &Es[s * 8]);
  }
  __syncthreads();

  short8 af[2][2];
#pragma unroll
  for (int m = 0; m < 2; ++m)
#pragma unroll
    for (int kb = 0; kb < 2; ++kb)
      af[m][kb] = *(const short8*)&Qs[(w * 32 + m * 16 + r) * 64 + kb * 32 + g * 8];

  f32x4 acc[2][5];
#pragma unroll
  for (int m = 0; m < 2; ++m)
#pragma unroll
    for (int n = 0; n < 5; ++n) acc[m][n] = fzero;

#pragma unroll
  for (int kb = 0; kb < 2; ++kb)
#pragma unroll
    for (int n = 0; n < 5; ++n) {
      short8 bfr = *(const short8*)&Es[(n * 16 + r) * 64 + kb * 32 + g * 8];
#pragma unroll
      for (int m = 0; m < 2; ++m)
        acc[m][n] = __builtin_amdgcn_mfma_f32_16x16x32_bf16(af[m][kb], bfr, acc[m][n], 0, 0, 0);
    }

  int p = r;  // col = n*16 + r
#pragma unroll
  for (int m = 0; m < 2; ++m) {
#pragma unroll
    for (int n = 0; n < 5; ++n) {
      int pp = n * 16 + p;
      if (pp < NPOS) {
#pragma unroll
        for (int j = 0; j < 4; ++j) {
          long row = (long)blockIdx.x * 128 + w * 32 + m * 16 + g * 4 + j;
          qd[row * NPOS + pp] = f2bf(acc[m][n][j]);
        }
      }
    }
  }
}

// Flash attention (round-14 verified best). Swapped-operand layout, log2
// domain, NO-SHIFT softmax (p = exp2(s + bias); score range cannot overflow
// fp32). l via ones-MFMA. qd precomputed in global memory; LDS = K/V
// double-buffer only (32 KB). T3 2-phase pipeline; grid (NH*BATCH, SEQ/128)
// for XCD K/V L2 locality. V input pre-transposed [b,h,d,l]. 16B-slot XOR
// swizzle on K/V LDS via pre-swizzled global source (linear gload_lds dest).
__global__ __launch_bounds__(256, 3) void attn_kernel(const short* __restrict__ Qg,
                                                      const short* __restrict__ Kg,
                                                      const short* __restrict__ Vg,
                                                      const short* __restrict__ qdG,
                                                      short* __restrict__ ctx) {
  // arena 32K: buf0 {Ks 8K | Vt 8K} @0, buf1 @16384. Prologue alias: Qs@0 (16K)
  __shared__ __align__(16) char arena[32768];
  short* Qs = (short*)arena;  // prologue alias

  const f32x4 fzero = {0.f, 0.f, 0.f, 0.f};
  int t = threadIdx.x;
  int w = t >> 6, lane = t & 63;
  int g = lane >> 4, r = lane & 15;
  int h = blockIdx.x & (NH - 1), b = blockIdx.x >> 4, qt = blockIdx.y;
  int q0 = qt * 128;
  const short* Qp = Qg + ((long)(b * NH + h) * SEQ + q0) * HD;
  const short* Kp = Kg + (long)(b * NH + h) * SEQ * HD;
  const short* VTp = Vg + (long)(b * NH + h) * HD * SEQ;  // [d][l]

  // ---- prologue: stage Q (linear, 16KB = 4 chunks x 256 lanes x 16B) ----
#pragma unroll
  for (int c = 0; c < 4; ++c)
    gload_lds16(Qp + c * 2048 + t * 8, &Qs[c * 2048 + t * 8]);
  __syncthreads();

  // hoist Q B-fragments: wave w owns q rows w*32..w*32+31, sub-tiles hq=0,1
  short8 aq[2][2];
#pragma unroll
  for (int hq = 0; hq < 2; ++hq)
#pragma unroll
    for (int kb = 0; kb < 2; ++kb)
      aq[hq][kb] = *(const short8*)&Qs[(w * 32 + hq * 16 + r) * 64 + kb * 32 + g * 8];
  __syncthreads();  // all Qs reads done; buf0 reusable

  // per-q bias rows in global qd (computed by qd_kernel)
  long qrow0 = (long)(b * NH + h) * SEQ + q0 + w * 32 + r;
  long qrow1 = qrow0 + 16;
  const short* qd0 = qdG + qrow0 * NPOS;
  const short* qd1 = qdG + qrow1 * NPOS;
  float bl0 = bf2f(qd0[0]), br0 = bf2f(qd0[72]);
  float bl1 = bf2f(qd1[0]), br1 = bf2f(qd1[72]);

  // staging sources (16B-slot XOR swizzle via global address, linear rows)
  int srow = lane >> 3;
  int ssl = ((lane & 7) ^ srow) * 8;
  const short* K0 = Kp + (long)(w * 16 + srow) * HD + ssl;
  const short* K1 = Kp + (long)(w * 16 + 8 + srow) * HD + ssl;
  const short* V0 = VTp + (long)(w * 16 + srow) * SEQ + ssl;
  const short* V1 = VTp + (long)(w * 16 + 8 + srow) * SEQ + ssl;
  int e0 = w * 1024 + lane * 8;
  int e1 = e0 + 512;
  int rx = (r & 7) << 3;
  int Lw = q0 + w * 32;

  // pipeline prologue: stage tile 0 into buf0 (Qs is dead past the barrier)
  {
    short* kb = (short*)arena;
    short* vb = kb + 4096;
    gload_lds16(K0, &kb[e0]);
    gload_lds16(K1, &kb[e1]);
    gload_lds16(V0, &vb[e0]);
    gload_lds16(V1, &vb[e1]);
  }
  __syncthreads();  // tile 0 staged (implicit vmcnt(0) drain)

  f32x4 o0[4], o1[4], lc0 = fzero, lc1 = fzero;
#pragma unroll
  for (int n = 0; n < 4; ++n) { o0[n] = fzero; o1[n] = fzero; }

  const short8 ones8 = {0x3F80, 0x3F80, 0x3F80, 0x3F80, 0x3F80, 0x3F80, 0x3F80, 0x3F80};
  union U8 { unsigned u[4]; short8 v; };

  for (int kt = 0; kt < 32; ++kt) {
    // stage NEXT tile into the other buffer; latency hides under this tile's
    // compute; the end-of-iteration barrier drains it. kt=31 wraps (harmless).
    {
      int kvn = ((kt + 1) & 31) * 64;
      short* kb = (short*)(arena + (((kt + 1) & 1) << 14));
      short* vb = kb + 4096;
      gload_lds16(K0 + (long)kvn * HD, &kb[e0]);
      gload_lds16(K1 + (long)kvn * HD, &kb[e1]);
      gload_lds16(V0 + kvn, &vb[e0]);
      gload_lds16(V1 + kvn, &vb[e1]);
    }
    const short* Ks = (const short*)(arena + ((kt & 1) << 14));
    const short* Vt = Ks + 4096;
    int kv0 = kt * 64;

    // S^T = K Q^T: C rows = keys (n*16+g*4+j), col = q (r). K-frag shared hq.
    f32x4 s0[4], s1[4];
#pragma unroll
    for (int n = 0; n < 4; ++n) { s0[n] = fzero; s1[n] = fzero; }
#pragma unroll
    for (int kb = 0; kb < 2; ++kb)
#pragma unroll
      for (int n = 0; n < 4; ++n) {
        short8 kfr = *(const short8*)&Ks[(n * 16 + r) * 64 + ((kb * 32 + g * 8) ^ rx)];
        s0[n] = __builtin_amdgcn_mfma_f32_16x16x32_bf16(kfr, aq[0][kb], s0[n], 0, 0, 0);
        s1[n] = __builtin_amdgcn_mfma_f32_16x16x32_bf16(kfr, aq[1][kb], s1[n], 0, 0, 0);
      }

    // relative bias: wave-uniform clamped fast path (29/32 tiles), then
    // p = exp2(s + b) directly — no max subtraction (shift-free softmax)
    bool allL = (kv0 + 63) <= (Lw - 64);
    bool allR = kv0 >= (Lw + 31 + 8);
    if (allL || allR) {
      float b0 = allL ? bl0 : br0;
      float b1 = allL ? bl1 : br1;
#pragma unroll
      for (int n = 0; n < 4; ++n)
#pragma unroll
        for (int j = 0; j < 4; ++j) { s0[n][j] += b0; s1[n][j] += b1; }
    } else {
      int lq = q0 + w * 32 + r;
#pragma unroll
      for (int n = 0; n < 4; ++n) {
        int key = kv0 + n * 16 + g * 4;
#pragma unroll
        for (int j = 0; j < 4; ++j) {
          int d0i = key + j - lq;
          d0i = d0i < -64 ? -64 : (d0i > 8 ? 8 : d0i);
          int d1i = key + j - lq - 16;
          d1i = d1i < -64 ? -64 : (d1i > 8 ? 8 : d1i);
          s0[n][j] += bf2f(qd0[d0i + 64]);
          s1[n][j] += bf2f(qd1[d1i + 64]);
        }
      }
    }

#pragma unroll
    for (int n = 0; n < 4; ++n)
#pragma unroll
      for (int j = 0; j < 4; ++j) {
        s0[n][j] = __builtin_amdgcn_exp2f(s0[n][j]);
        s1[n][j] = __builtin_amdgcn_exp2f(s1[n][j]);
      }

    // O^T += V^T P^T : A = V^T-frag (k-permuted to match), B = P from regs.
    // l accumulated by ones-MFMA (order-immune sum over all 32 keys).
#pragma unroll
    for (int w32 = 0; w32 < 2; ++w32) {
      U8 pb0, pb1;
      pb0.u[0] = pkbf(s0[2 * w32][0], s0[2 * w32][1]);
      pb0.u[1] = pkbf(s0[2 * w32][2], s0[2 * w32][3]);
      pb0.u[2] = pkbf(s0[2 * w32 + 1][0], s0[2 * w32 + 1][1]);
      pb0.u[3] = pkbf(s0[2 * w32 + 1][2], s0[2 * w32 + 1][3]);
      pb1.u[0] = pkbf(s1[2 * w32][0], s1[2 * w32][1]);
      pb1.u[1] = pkbf(s1[2 * w32][2], s1[2 * w32][3]);
      pb1.u[2] = pkbf(s1[2 * w32 + 1][0], s1[2 * w32 + 1][1]);
      pb1.u[3] = pkbf(s1[2 * w32 + 1][2], s1[2 * w32 + 1][3]);
      lc0 = __builtin_amdgcn_mfma_f32_16x16x32_bf16(ones8, pb0.v, lc0, 0, 0, 0);
      lc1 = __builtin_amdgcn_mfma_f32_16x16x32_bf16(ones8, pb1.v, lc1, 0, 0, 0);
      // V^T cols w32*32 + {g*4..+3, 16+g*4..+3}, 16B-slot swizzled by row
      int cA = (((w32 * 4 + (g >> 1)) ^ (r & 7)) << 3) + ((g & 1) * 4);
      int cB = (((w32 * 4 + 2 + (g >> 1)) ^ (r & 7)) << 3) + ((g & 1) * 4);
#pragma unroll
      for (int n = 0; n < 4; ++n) {
        const short* vrow = &Vt[(n * 16 + r) * 64];
        short4v va_ = *(const short4v*)(vrow + cA);
        short4v vb_ = *(const short4v*)(vrow + cB);
        short8 v8;
        v8[0] = va_[0]; v8[1] = va_[1]; v8[2] = va_[2]; v8[3] = va_[3];
        v8[4] = vb_[0]; v8[5] = vb_[1]; v8[6] = vb_[2]; v8[7] = vb_[3];
        o0[n] = __builtin_amdgcn_mfma_f32_16x16x32_bf16(v8, pb0.v, o0[n], 0, 0, 0);
        o1[n] = __builtin_amdgcn_mfma_f32_16x16x32_bf16(v8, pb1.v, o1[n], 0, 0, 0);
      }
    }
    __syncthreads();  // all reads of this buffer done; next-tile stage drained
  }

  // epilogue: lc cols hold full l for q=r (rows identical); normalize, store
  float inv0 = 1.f / lc0[0], inv1 = 1.f / lc1[0];
  long grow0 = (long)(b * SEQ + q0 + w * 32 + r);
  long grow1 = grow0 + 16;
#pragma unroll
  for (int n = 0; n < 4; ++n) {
    uint2 v0, v1;
    v0.x = pkbf(o0[n][0] * inv0, o0[n][1] * inv0);
    v0.y = pkbf(o0[n][2] * inv0, o0[n][3] * inv0);
    v1.x = pkbf(o1[n][0] * inv1, o1[n][1] * inv1);
    v1.y = pkbf(o1[n][2] * inv1, o1[n][3] * inv1);
    *(uint2*)&ctx[grow0 * HID + h * 64 + n * 16 + g * 4] = v0;
    *(uint2*)&ctx[grow1 * HID + h * 64 + n * 16 + g * 4] = v1;
  }
}

extern "C" void kernel_launch(void* const* d_in, const int* in_sizes, int n_in,
                              void* d_out, int out_size, void* d_ws, size_t ws_size,
                              hipStream_t stream) {
  if (n_in < 10) return;
  const float* hs = (const float*)d_in[0];
  const float* Wq = (const float*)d_in[1];
  const float* bq = (const float*)d_in[2];
  const float* Wk = (const float*)d_in[3];
  const float* bk = (const float*)d_in[4];
  const float* Wv = (const float*)d_in[5];
  const float* bv = (const float*)d_in[6];
  const float* Wo = (const float*)d_in[7];
  const float* bo = (const float*)d_in[8];
  const float* de = (const float*)d_in[9];

  char* ws = (char*)d_ws;
  size_t off = 0;
  auto alloc = [&](size_t bytes) {
    size_t o = off;
    off += (bytes + 255) & ~(size_t)255;
    return o;
  };
  const size_t ACT = (size_t)BATCH * SEQ * HID * 2;  // 16 MB bf16
  const size_t WMT = (size_t)HID * HID * 2;          // 2 MB bf16
  short* hB  = (short*)(ws + alloc(ACT));
  short* wqB = (short*)(ws + alloc(WMT));
  short* wkB = (short*)(ws + alloc(WMT));
  short* wvB = (short*)(ws + alloc(WMT));
  short* woB = (short*)(ws + alloc(WMT));
  short* deB = (short*)(ws + alloc((size_t)NPOS * HD * 2));
  short* qB  = (short*)(ws + alloc(ACT));
  short* kB  = (short*)(ws + alloc(ACT));
  short* vB  = (short*)(ws + alloc(ACT));  // V^T layout [b,h,d,l]
  short* qdB = (short*)(ws + alloc((size_t)BATCH * NH * SEQ * NPOS * 2));  // 19.1 MB
  short* ctxB = hB;  // hB dead after QKV GEMMs; reuse for attention output

  // one fused conversion launch: hs (8192 blocks) | 4 weights (4096) | de (5)
  {
    long total4 = (long)BATCH * SEQ * HID / 4 + 4L * (HID * HID / 4) + NPOS * HD / 4;
    int nblk = (int)((total4 + 255) / 256);
    cvt_all<<<dim3(nblk), dim3(256), 0, stream>>>(hs, Wq, Wk, Wv, Wo, de,
                                                  hB, wqB, wkB, wvB, woB, deB);
  }

  // Q pre-scaled by (1/sqrt(64)) * log2(e) so attention works in exp2 domain
  const float QSCALE = 0.125f * 1.4426950408889634f;
  dim3 gg(BATCH * SEQ / 128, HID / 128), blk(256);
  gemm_nt<0><<<gg, blk, 0, stream>>>(hB, wqB, bq, qB, QSCALE);
  gemm_nt<0><<<gg, blk, 0, stream>>>(hB, wkB, bk, kB, 1.0f);
  gemm_nt<2><<<gg, blk, 0, stream>>>(hB, wvB, bv, vB, 1.0f);    // V transposed

  // qd[row][p] = Q·DE^T (inherits QSCALE*log2e from qB) — 2.4 GFLOP MFMA
  qd_kernel<<<dim3(BATCH * NH * SEQ / 128), blk, 0, stream>>>(qB, deB, qdB);

  attn_kernel<<<dim3(NH * BATCH, SEQ / 128), blk, 0, stream>>>(qB, kB, vB, qdB, ctxB);

  gemm_nt<1><<<gg, blk, 0, stream>>>(ctxB, woB, bo, d_out, 1.0f);
}